// Round 11
// baseline (65.644 us; speedup 1.0000x reference)
//
#include <hip/hip_runtime.h>

typedef __bf16 bhalf;
typedef bhalf bhalf8 __attribute__((ext_vector_type(8)));
typedef float f32x4 __attribute__((ext_vector_type(4)));
typedef unsigned short u16;
typedef u16 u16x8 __attribute__((ext_vector_type(8)));

__device__ __forceinline__ u16 f2bf(float f) {
  union { float f; unsigned u; } v; v.f = f;
  unsigned r = v.u + 0x7FFFu + ((v.u >> 16) & 1u);
  return (u16)(r >> 16);
}

// XOR swizzle keyed on bits 7-9; involution; <=2-way banks on frag reads (measured 0 conflicts).
__device__ __forceinline__ int swz(int L) { return L ^ (((L >> 7) & 7) << 4); }

#define GLL16(gp, lp) __builtin_amdgcn_global_load_lds( \
    (const __attribute__((address_space(1))) unsigned int*)(gp), \
    (__attribute__((address_space(3))) unsigned int*)(lp), 16, 0, 0)

// W0: [512][784] f32 -> bf16 [512][800] zero-pad; W1: [256][512]; W2: [10][256]->[16][256].
#define KP0 800
#define W0E (512 * KP0)
#define W1E (256 * 512)
#define W2E (16 * 256)

__global__ __launch_bounds__(256) void cvt_weights(
    const float* __restrict__ W0, const float* __restrict__ W1,
    const float* __restrict__ W2,
    u16* __restrict__ W0b, u16* __restrict__ W1b, u16* __restrict__ W2b)
{
  int i = blockIdx.x * 256 + threadIdx.x;
  if (i < W0E) {
    int r = i / KP0, k = i - r * KP0;
    W0b[i] = (k < 784) ? f2bf(W0[r * 784 + k]) : (u16)0;
    return;
  }
  i -= W0E;
  if (i < W1E) { W1b[i] = f2bf(W1[i]); return; }
  i -= W1E;
  if (i < W2E) {
    int r = i >> 8, c = i & 255;
    W2b[i] = (r < 10) ? f2bf(W2[r * 256 + c]) : (u16)0;
  }
}

// m1 = relu(x @ W0^T): FULL-N tile 128x512 (x read ONCE), BK=32, 8 waves (2Mx4N,
// wave 64x128, acc[4][8]), dbuf 80KB dynamic LDS, 2-phase counted-vmcnt schedule.
// A: f32 reg-staged + cvt (1 chunk/thread); B: 4 gll/wave pre-swizzled. 25 K-tiles.
__global__ __launch_bounds__(512) void gemm1_fn(
    const float* __restrict__ x, const u16* __restrict__ Wb, u16* __restrict__ Cp)
{
  extern __shared__ u16 lds[];  // bytes: A0 @0, A1 @8192, B0 @16384, B1 @49152 (80 KB)
  const int t = threadIdx.x, w = t >> 6, lane = t & 63;
  const size_t rbase = (size_t)blockIdx.x * 128;
  const int wr = w >> 2, wc = w & 3, fr = lane & 15, fg = lane >> 4;

  // fragment byte offsets (64B rows, swizzled)
  int aO[4], bO[8];
#pragma unroll
  for (int m = 0; m < 4; ++m) aO[m] = swz((wr * 64 + m * 16 + fr) * 64 + fg * 16);
#pragma unroll
  for (int n = 0; n < 8; ++n) bO[n] = swz((wc * 128 + n * 16 + fr) * 64 + fg * 16);

  // B staging: 32KB tile = 4 x 1KB gll per wave; source pre-swizzled
  const u16* bSrc[4];
#pragma unroll
  for (int i = 0; i < 4; ++i) {
    int P = (w * 4 + i) * 1024 + lane * 16;
    int U = swz(P);
    bSrc[i] = Wb + (size_t)(U >> 6) * KP0 + ((U & 63) >> 1);
  }

  // A staging: 1 chunk/thread (16B bf16 dest = 8 f32 src)
  const float* xRow; int aKe;
  {
    int P = t * 16;
    int U = swz(P);
    xRow = x + (rbase + (U >> 6)) * (size_t)784;
    aKe = (U & 63) >> 1;
  }

  f32x4 acc[4][8];
#pragma unroll
  for (int m = 0; m < 4; ++m)
#pragma unroll
    for (int n = 0; n < 8; ++n) acc[m][n] = (f32x4){0.f, 0.f, 0.f, 0.f};

  f32x4 xr0, xr1;
  bhalf8 bf[8], afA[4];

  auto loadX = [&](int s) {
    int gk = s * 32 + aKe;
    const float* p = xRow + ((gk < 784) ? gk : 0);   // clamp; W0b zero-padded there
    xr0 = *(const f32x4*)p; xr1 = *(const f32x4*)(p + 4);
  };
  auto cvtW = [&](int aBase) {
    u16x8 v;
#pragma unroll
    for (int j = 0; j < 4; ++j) { v[j] = f2bf(xr0[j]); v[4 + j] = f2bf(xr1[j]); }
    *(u16x8*)((char*)lds + aBase + t * 16) = v;
  };
  auto stageB = [&](int s, int bBase) {
#pragma unroll
    for (int i = 0; i < 4; ++i)
      GLL16(bSrc[i] + s * 32, (char*)lds + bBase + (w * 4 + i) * 1024);
  };
  auto rdA = [&](int aB) {
#pragma unroll
    for (int m = 0; m < 4; ++m) afA[m] = *(const bhalf8*)((const char*)lds + aB + aO[m]);
  };
  auto rdB = [&](int bB) {
#pragma unroll
    for (int n = 0; n < 8; ++n) bf[n] = *(const bhalf8*)((const char*)lds + bB + bO[n]);
  };
  auto mfmaLo = [&]() {
    __builtin_amdgcn_s_setprio(1);
#pragma unroll
    for (int m = 0; m < 4; ++m)
#pragma unroll
      for (int n = 0; n < 4; ++n)
        acc[m][n] = __builtin_amdgcn_mfma_f32_16x16x32_bf16(afA[m], bf[n], acc[m][n], 0, 0, 0);
    __builtin_amdgcn_s_setprio(0);
  };
  auto mfmaHi = [&]() {
    __builtin_amdgcn_s_setprio(1);
#pragma unroll
    for (int m = 0; m < 4; ++m)
#pragma unroll
      for (int n = 4; n < 8; ++n)
        acc[m][n] = __builtin_amdgcn_mfma_f32_16x16x32_bf16(afA[m], bf[n], acc[m][n], 0, 0, 0);
    __builtin_amdgcn_s_setprio(0);
  };

  // ---- prologue: tile0 staged, tile1 in flight ----
  loadX(0);
  stageB(0, 16384);
  cvtW(0);                 // auto-waits x(0) via reg dep; B glls keep flying
  loadX(1);
  stageB(1, 16384 + 32768);
  asm volatile("s_waitcnt vmcnt(6) lgkmcnt(0)" ::: "memory");  // B(0) landed, A0 written
  __builtin_amdgcn_s_barrier();

  // ---- steady: tiles 0..22 ----
  for (int tt = 0; tt < 23; ++tt) {
    const int c = tt & 1;
    const int aB = c * 8192;
    const int bB = 16384 + c * 32768;
    // phase A: 12 frag reads + MFMA n0..3 (compiler fine-grains lgkm waits)
    rdA(aB); rdB(bB);
    mfmaLo();
    asm volatile("s_waitcnt lgkmcnt(0)" ::: "memory");   // all reads of buf[c] done
    __builtin_amdgcn_s_barrier();
    // phase B: stage A(tt+1) regs->LDS, issue tt+2, MFMA n4..7 overlapped
    cvtW(aB ^ 8192);       // auto-waits x(tt+1)
    loadX(tt + 2);
    stageB(tt + 2, bB);    // into just-freed B[c]
    mfmaHi();
    asm volatile("s_waitcnt vmcnt(6) lgkmcnt(0)" ::: "memory");  // B(tt+1) landed
    __builtin_amdgcn_s_barrier();
  }
  // ---- tail: tt=23, 24 ----
  {
    rdA(8192); rdB(16384 + 32768);       // tile 23 in buf1
    mfmaLo();
    asm volatile("s_waitcnt lgkmcnt(0)" ::: "memory");
    __builtin_amdgcn_s_barrier();
    cvtW(0);                              // A(24) -> buf0 (x(24) loaded at tt=22)
    mfmaHi();
    asm volatile("s_waitcnt vmcnt(0) lgkmcnt(0)" ::: "memory");  // drain B(24) glls
    __builtin_amdgcn_s_barrier();

    rdA(0); rdB(16384);                   // tile 24 in buf0
    mfmaLo();
    mfmaHi();
  }

  // epilogue: relu -> bf16
#pragma unroll
  for (int m = 0; m < 4; ++m)
#pragma unroll
    for (int n = 0; n < 8; ++n)
#pragma unroll
      for (int q = 0; q < 4; ++q) {
        size_t row = rbase + wr * 64 + m * 16 + fg * 4 + q;
        size_t col = (size_t)wc * 128 + n * 16 + fr;
        float vv = acc[m][n][q];
        vv = vv > 0.f ? vv : 0.f;
        Cp[row * 512 + col] = f2bf(vv);
      }
}

// Fused layers 2+3 (proven r5/r8 version): 64 rows x full 256 cols, 8 waves (2x4),
// BK=32, 16 steps, all-GLL dbuf, 2 blocks/CU.
__global__ __launch_bounds__(512, 4) void gemm23(
    const u16* __restrict__ m1, const u16* __restrict__ W1b,
    const u16* __restrict__ W2b, float* __restrict__ out)
{
  __shared__ u16 pool[20480];
  __shared__ u16 W2s[16][264];
  const int t = threadIdx.x, w = t >> 6, lane = t & 63;
  const size_t rbase = (size_t)blockIdx.x * 64;
  const int wr = w >> 2, wc = w & 3, fr = lane & 15, fg = lane >> 4;

  {
    int r = t >> 5, kc = (t & 31) * 8;
    *(int4*)&W2s[r][kc] = *(const int4*)(W2b + r * 256 + kc);
  }

  int aOff[2], bOff[4];
#pragma unroll
  for (int i = 0; i < 2; ++i) aOff[i] = swz((wr * 32 + i * 16 + fr) * 64 + fg * 16);
#pragma unroll
  for (int j = 0; j < 4; ++j) bOff[j] = swz((wc * 64 + j * 16 + fr) * 64 + fg * 16);

  const u16* aSrc = nullptr; int aDst = 0;
  if (w < 4) {
    int Dl = (w * 64 + lane) * 16;
    int Ul = swz(Dl);
    aSrc = m1 + (rbase + (Ul >> 6)) * 512 + ((Ul & 63) >> 1);
    aDst = (w * 64) * 16;
  }
  const u16* bSrc[2]; int bDst[2];
#pragma unroll
  for (int i = 0; i < 2; ++i) {
    int Dl = (w * 128 + i * 64 + lane) * 16;
    int Ul = swz(Dl);
    bSrc[i] = W1b + (Ul >> 6) * 512 + ((Ul & 63) >> 1);
    bDst[i] = 8192 + (w * 128 + i * 64) * 16;
  }

  f32x4 acc[2][4];
#pragma unroll
  for (int i = 0; i < 2; ++i)
#pragma unroll
    for (int j = 0; j < 4; ++j) acc[i][j] = (f32x4){0.f, 0.f, 0.f, 0.f};

  if (w < 4) GLL16(aSrc, (char*)pool + aDst);
#pragma unroll
  for (int i = 0; i < 2; ++i) GLL16(bSrc[i], (char*)pool + bDst[i]);

  for (int tt = 0; tt < 16; ++tt) {
    const int cur = tt & 1;
    const char* Asc = (const char*)pool + cur * 4096;
    const char* Bsc = (const char*)pool + 8192 + cur * 16384;
    asm volatile("s_waitcnt vmcnt(0)" ::: "memory");
    __syncthreads();

    if (tt < 15) {
      const int k0 = (tt + 1) * 32;
      if (w < 4) GLL16(aSrc + k0, (char*)pool + (cur ^ 1) * 4096 + aDst);
#pragma unroll
      for (int i = 0; i < 2; ++i)
        GLL16(bSrc[i] + k0, (char*)pool + (cur ^ 1) * 16384 + bDst[i]);
    }

    bhalf8 af[2], bfv[4];
#pragma unroll
    for (int i = 0; i < 2; ++i) af[i] = *(const bhalf8*)(Asc + aOff[i]);
#pragma unroll
    for (int j = 0; j < 4; ++j) bfv[j] = *(const bhalf8*)(Bsc + bOff[j]);
#pragma unroll
    for (int i = 0; i < 2; ++i)
#pragma unroll
      for (int j = 0; j < 4; ++j)
        acc[i][j] = __builtin_amdgcn_mfma_f32_16x16x32_bf16(af[i], bfv[j], acc[i][j], 0, 0, 0);
  }

  __syncthreads();
#pragma unroll
  for (int i = 0; i < 2; ++i)
#pragma unroll
    for (int j = 0; j < 4; ++j)
#pragma unroll
      for (int q = 0; q < 4; ++q) {
        int row = wr * 32 + i * 16 + fg * 4 + q;
        int col = wc * 64 + j * 16 + fr;
        float vv = acc[i][j][q];
        vv = vv > 0.f ? vv : 0.f;
        pool[row * 264 + col] = f2bf(vv);
      }
  __syncthreads();

  if (w < 4) {
    f32x4 acc3 = (f32x4){0.f, 0.f, 0.f, 0.f};
    const int arow = w * 16 + fr;
#pragma unroll
    for (int ks = 0; ks < 8; ++ks) {
      bhalf8 a = *(const bhalf8*)&pool[arow * 264 + ks * 32 + fg * 8];
      bhalf8 b = *(const bhalf8*)&W2s[fr][ks * 32 + fg * 8];
      acc3 = __builtin_amdgcn_mfma_f32_16x16x32_bf16(a, b, acc3, 0, 0, 0);
    }
    if (fr < 10) {
#pragma unroll
      for (int q = 0; q < 4; ++q) {
        size_t row = rbase + w * 16 + fg * 4 + q;
        float vv = acc3[q];
        out[row * 10 + fr] = vv > 0.f ? vv : 0.f;
      }
    }
  }
}

extern "C" void kernel_launch(void* const* d_in, const int* in_sizes, int n_in,
                              void* d_out, int out_size, void* d_ws, size_t ws_size,
                              hipStream_t stream) {
  const float* x  = (const float*)d_in[0];
  const float* W0 = (const float*)d_in[1];
  const float* W1 = (const float*)d_in[2];
  const float* W2 = (const float*)d_in[3];
  float* out = (float*)d_out;

  char* ws = (char*)d_ws;
  u16* m1  = (u16*)(ws);                    // 32768x512 bf16 = 33554432 B
  u16* W0b = (u16*)(ws + 33554432);         // 512x800 = 819200 B
  u16* W1b = (u16*)(ws + 34373632);         // 256x512 = 262144 B
  u16* W2b = (u16*)(ws + 34635776);         // 16x256  = 8192 B

  // allow 80 KB dynamic LDS for gemm1_fn (idempotent, host-side, no enqueue)
  hipFuncSetAttribute((const void*)gemm1_fn,
                      hipFuncAttributeMaxDynamicSharedMemorySize, 81920);

  cvt_weights<<<dim3((W0E + W1E + W2E + 255) / 256), dim3(256), 0, stream>>>(
      W0, W1, W2, W0b, W1b, W2b);

  // m1 = relu(x @ W0^T): 256 row-tiles, full N=512 per block (x read once)
  gemm1_fn<<<dim3(256), dim3(512), 81920, stream>>>(x, W0b, m1);

  // out = relu(relu(m1 @ W1^T) @ W2^T)
  gemm23<<<dim3(512), dim3(512), 0, stream>>>(m1, W1b, W2b, out);
}

// Round 12
// 62.757 us; speedup vs baseline: 1.0460x; 1.0460x over previous
//
#include <hip/hip_runtime.h>

typedef __bf16 bhalf;
typedef bhalf bhalf8 __attribute__((ext_vector_type(8)));
typedef float f32x4 __attribute__((ext_vector_type(4)));
typedef unsigned short u16;
typedef u16 u16x8 __attribute__((ext_vector_type(8)));

__device__ __forceinline__ u16 f2bf(float f) {
  union { float f; unsigned u; } v; v.f = f;
  unsigned r = v.u + 0x7FFFu + ((v.u >> 16) & 1u);
  return (u16)(r >> 16);
}

// XOR swizzle: flips byte bits 4-6 by bits 7-9; involution; conflict-free proven r5-r11.
__device__ __forceinline__ int swz(int L) { return L ^ (((L >> 7) & 7) << 4); }

#define GLL16(gp, lp) __builtin_amdgcn_global_load_lds( \
    (const __attribute__((address_space(1))) unsigned int*)(gp), \
    (__attribute__((address_space(3))) unsigned int*)(lp), 16, 0, 0)

#define SB() __builtin_amdgcn_sched_barrier(0)

// W0: [512][784] f32 -> bf16 [512][832] zero-pad (13 K-tiles of 64); W1: [256][512]; W2 pad 16x256.
#define KP0 832
#define W0E (512 * KP0)
#define W1E (256 * 512)
#define W2E (16 * 256)

__global__ __launch_bounds__(256) void cvt_weights(
    const float* __restrict__ W0, const float* __restrict__ W1,
    const float* __restrict__ W2,
    u16* __restrict__ W0b, u16* __restrict__ W1b, u16* __restrict__ W2b)
{
  int i = blockIdx.x * 256 + threadIdx.x;
  if (i < W0E) {
    int r = i / KP0, k = i - r * KP0;
    W0b[i] = (k < 784) ? f2bf(W0[r * 784 + k]) : (u16)0;
    return;
  }
  i -= W0E;
  if (i < W1E) { W1b[i] = f2bf(W1[i]); return; }
  i -= W1E;
  if (i < W2E) {
    int r = i >> 8, c = i & 255;
    W2b[i] = (r < 10) ? f2bf(W2[r * 256 + c]) : (u16)0;
  }
}

// m1 = relu(x @ W0^T): m201-style 8-phase port. Tile 128x512 (full N, x read once),
// BK=64, 8 waves (2Mx4N, wave 64x128, acc[4][8]). 4 phases/K-tile x 16 MFMA.
// A: [128][64] dbuf 2x16KB, f32 reg-staged + cvt, 2-tile x lead.
// B: [512][32] k-sub half-tiles, 3-buffer rotation (3x32KB) via gll, pre-swizzled.
// vmcnt(4)@Ph2 / vmcnt(8)@Ph4 (exact queue arithmetic), raw s_barrier pairs, setprio.
__global__ __launch_bounds__(512) void gemm1_p8(
    const float* __restrict__ x, const u16* __restrict__ Wb, u16* __restrict__ Cp)
{
  extern __shared__ u16 ldsu[];      // bytes: A0@0 A1@16384 | B bufs @32768+32768*(H%3)
  char* lds = (char*)ldsu;
  const int t = threadIdx.x, w = t >> 6, lane = t & 63;
  const size_t rbase = (size_t)blockIdx.x * 128;
  const int wr = w >> 2, wc = w & 3, fr = lane & 15, fg = lane >> 4;

  // A frags: [128 rows][64 k] (128B rows): byte = row*128 + fg*16, ksub via ^64
  int aO[4];
#pragma unroll
  for (int m = 0; m < 4; ++m) aO[m] = swz((wr * 64 + m * 16 + fr) * 128 + fg * 16);
  // B frags: half-tile [512 rows][32 k] (64B rows); bO[j+4] = bO[j]+4096
  int bO[4];
#pragma unroll
  for (int j = 0; j < 4; ++j) bO[j] = swz((wc * 128 + j * 16 + fr) * 64 + fg * 16);

  // B staging: 4 gll-chunks/wave per half-tile; source pre-swizzled
  const u16* bSrcP[4];
#pragma unroll
  for (int i = 0; i < 4; ++i) {
    int P = (w * 4 + i) * 1024 + lane * 16;
    int U = swz(P);
    bSrcP[i] = Wb + (size_t)(U >> 6) * KP0 + ((U & 63) >> 1);
  }
  // A staging: 2 chunks/thread (16B bf16 dest = 8 f32 src)
  const float* xRow[2]; int aKc[2];
#pragma unroll
  for (int c2 = 0; c2 < 2; ++c2) {
    int P = c2 * 8192 + t * 16;
    int U = swz(P);
    xRow[c2] = x + (rbase + (U >> 7)) * (size_t)784;
    aKc[c2] = (U & 127) >> 1;
  }

  f32x4 acc[4][8];
#pragma unroll
  for (int m = 0; m < 4; ++m)
#pragma unroll
    for (int n = 0; n < 8; ++n) acc[m][n] = (f32x4){0.f, 0.f, 0.f, 0.f};

  bhalf8 afA[4], bf[4];
  f32x4 xrE[2][2], xrO[2][2];

  auto loadX = [&](int tt2, f32x4 (&xr)[2][2]) {
#pragma unroll
    for (int c2 = 0; c2 < 2; ++c2) {
      int k = tt2 * 64 + aKc[c2];
      const float* p = xRow[c2] + ((k < 784) ? k : 0);   // clamp: W0b zero-padded
      xr[c2][0] = *(const f32x4*)p; xr[c2][1] = *(const f32x4*)(p + 4);
    }
  };
  auto cvtW = [&](int aB, f32x4 (&xr)[2][2]) {
#pragma unroll
    for (int c2 = 0; c2 < 2; ++c2) {
      u16x8 v;
#pragma unroll
      for (int j = 0; j < 4; ++j) { v[j] = f2bf(xr[c2][0][j]); v[4 + j] = f2bf(xr[c2][1][j]); }
      *(u16x8*)(lds + aB + c2 * 8192 + t * 16) = v;
    }
  };
  auto gllLo = [&](int H) {     // chunks 0,1 of half-tile H -> buf H%3
    char* bb = lds + 32768 + (H % 3) * 32768;
    GLL16(bSrcP[0] + H * 32, bb + (w * 4 + 0) * 1024);
    GLL16(bSrcP[1] + H * 32, bb + (w * 4 + 1) * 1024);
  };
  auto gllHi = [&](int H) {     // chunks 2,3
    char* bb = lds + 32768 + (H % 3) * 32768;
    GLL16(bSrcP[2] + H * 32, bb + (w * 4 + 2) * 1024);
    GLL16(bSrcP[3] + H * 32, bb + (w * 4 + 3) * 1024);
  };
  auto rdA = [&](int aB, int ks) {
#pragma unroll
    for (int m = 0; m < 4; ++m)
      afA[m] = *(const bhalf8*)(lds + aB + (aO[m] ^ (ks << 6)));
  };
  auto rdBq = [&](int H, int hi) {
    const char* bb = lds + 32768 + (H % 3) * 32768 + hi * 4096;
#pragma unroll
    for (int j = 0; j < 4; ++j) bf[j] = *(const bhalf8*)(bb + bO[j]);
  };
  auto mfmaLoQ = [&]() {
    __builtin_amdgcn_s_setprio(1);
#pragma unroll
    for (int m = 0; m < 4; ++m)
#pragma unroll
      for (int n = 0; n < 4; ++n)
        acc[m][n] = __builtin_amdgcn_mfma_f32_16x16x32_bf16(afA[m], bf[n], acc[m][n], 0, 0, 0);
    __builtin_amdgcn_s_setprio(0);
  };
  auto mfmaHiQ = [&]() {
    __builtin_amdgcn_s_setprio(1);
#pragma unroll
    for (int m = 0; m < 4; ++m)
#pragma unroll
      for (int n = 0; n < 4; ++n)
        acc[m][4 + n] = __builtin_amdgcn_mfma_f32_16x16x32_bf16(afA[m], bf[n], acc[m][4 + n], 0, 0, 0);
    __builtin_amdgcn_s_setprio(0);
  };

  // tile body: 4 phases, each {reads; stage; bar; lgkm0; 16 MFMA; [vm]; bar}
  auto tile = [&](int tt, f32x4 (&xrLd)[2][2], f32x4 (&xrCv)[2][2],
                  bool doStage, bool doX, int vmPh4, bool vm0Ph2) {
    const int aB = (tt & 1) * 16384;
    const int H0 = 2 * tt, H1 = 2 * tt + 1;
    // ---- Ph1: A(ks0) + B(ks0,lo) ----
    rdA(aB, 0); rdBq(H0, 0);
    if (doStage) gllLo(H0 + 2);
    __builtin_amdgcn_s_barrier();
    asm volatile("s_waitcnt lgkmcnt(0)" ::: "memory"); SB();
    mfmaLoQ();
    __builtin_amdgcn_s_barrier();
    // ---- Ph2: B(ks0,hi) ----
    rdBq(H0, 1);
    if (doStage) gllHi(H0 + 2);
    __builtin_amdgcn_s_barrier();
    asm volatile("s_waitcnt lgkmcnt(0)" ::: "memory"); SB();
    mfmaHiQ();
    if (vm0Ph2) { asm volatile("s_waitcnt vmcnt(0)" ::: "memory"); }
    else        { asm volatile("s_waitcnt vmcnt(4)" ::: "memory"); }
    __builtin_amdgcn_s_barrier();
    // ---- Ph3: A(ks1) + B(ks1,lo) ----
    rdA(aB, 1); rdBq(H1, 0);
    if (doStage) gllLo(H1 + 2);
    if (doX) loadX(tt + 2, xrLd);
    __builtin_amdgcn_s_barrier();
    asm volatile("s_waitcnt lgkmcnt(0)" ::: "memory"); SB();
    mfmaLoQ();
    __builtin_amdgcn_s_barrier();
    // ---- Ph4: B(ks1,hi) + A(tt+1) cvt ----
    rdBq(H1, 1);
    if (tt < 12) cvtW(aB ^ 16384, xrCv);
    if (doStage) gllHi(H1 + 2);
    __builtin_amdgcn_s_barrier();
    asm volatile("s_waitcnt lgkmcnt(0)" ::: "memory"); SB();
    mfmaHiQ();
    if (vmPh4 == 8)      { asm volatile("s_waitcnt vmcnt(8)" ::: "memory"); }
    else if (vmPh4 == 4) { asm volatile("s_waitcnt vmcnt(4)" ::: "memory"); }
    __builtin_amdgcn_s_barrier();
  };

  // ---- prologue: B(0) both halves, x(0), x(1), A(0) written ----
  gllLo(0); gllHi(0);          // h0 -> buf0
  gllLo(1); gllHi(1);          // h1 -> buf1
  loadX(0, xrE);
  loadX(1, xrO);
  cvtW(0, xrE);                // auto-drains h0,h1,x(0)
  asm volatile("s_waitcnt lgkmcnt(0)" ::: "memory");
  __builtin_amdgcn_s_barrier();

  // ---- tiles 0..9 ----
  for (int i = 0; i < 5; ++i) {
    tile(2 * i,     xrE, xrO, true, true, 8, false);
    tile(2 * i + 1, xrO, xrE, true, true, 8, false);
  }
  // ---- tiles 10, 11, 12 ----
  tile(10, xrE, xrO, true,  true,  8, false);
  tile(11, xrO, xrE, true,  false, 4, false);
  tile(12, xrE, xrO, false, false, -1, true);

  // epilogue: relu -> bf16
#pragma unroll
  for (int m = 0; m < 4; ++m)
#pragma unroll
    for (int n = 0; n < 8; ++n)
#pragma unroll
      for (int q = 0; q < 4; ++q) {
        size_t row = rbase + wr * 64 + m * 16 + fg * 4 + q;
        size_t col = (size_t)wc * 128 + n * 16 + fr;
        float vv = acc[m][n][q];
        vv = vv > 0.f ? vv : 0.f;
        Cp[row * 512 + col] = f2bf(vv);
      }
}

// Fused layers 2+3 (proven r5 version): 64 rows x full 256 cols, 8 waves (2x4),
// BK=32, 16 steps, all-GLL dbuf, 2 blocks/CU.
__global__ __launch_bounds__(512, 4) void gemm23(
    const u16* __restrict__ m1, const u16* __restrict__ W1b,
    const u16* __restrict__ W2b, float* __restrict__ out)
{
  __shared__ u16 pool[20480];
  __shared__ u16 W2s[16][264];
  const int t = threadIdx.x, w = t >> 6, lane = t & 63;
  const size_t rbase = (size_t)blockIdx.x * 64;
  const int wr = w >> 2, wc = w & 3, fr = lane & 15, fg = lane >> 4;

  {
    int r = t >> 5, kc = (t & 31) * 8;
    *(int4*)&W2s[r][kc] = *(const int4*)(W2b + r * 256 + kc);
  }

  int aOff[2], bOff[4];
#pragma unroll
  for (int i = 0; i < 2; ++i) aOff[i] = swz((wr * 32 + i * 16 + fr) * 64 + fg * 16);
#pragma unroll
  for (int j = 0; j < 4; ++j) bOff[j] = swz((wc * 64 + j * 16 + fr) * 64 + fg * 16);

  const u16* aSrc = nullptr; int aDst = 0;
  if (w < 4) {
    int Dl = (w * 64 + lane) * 16;
    int Ul = swz(Dl);
    aSrc = m1 + (rbase + (Ul >> 6)) * 512 + ((Ul & 63) >> 1);
    aDst = (w * 64) * 16;
  }
  const u16* bSrc[2]; int bDst[2];
#pragma unroll
  for (int i = 0; i < 2; ++i) {
    int Dl = (w * 128 + i * 64 + lane) * 16;
    int Ul = swz(Dl);
    bSrc[i] = W1b + (Ul >> 6) * 512 + ((Ul & 63) >> 1);
    bDst[i] = 8192 + (w * 128 + i * 64) * 16;
  }

  f32x4 acc[2][4];
#pragma unroll
  for (int i = 0; i < 2; ++i)
#pragma unroll
    for (int j = 0; j < 4; ++j) acc[i][j] = (f32x4){0.f, 0.f, 0.f, 0.f};

  if (w < 4) GLL16(aSrc, (char*)pool + aDst);
#pragma unroll
  for (int i = 0; i < 2; ++i) GLL16(bSrc[i], (char*)pool + bDst[i]);

  for (int tt = 0; tt < 16; ++tt) {
    const int cur = tt & 1;
    const char* Asc = (const char*)pool + cur * 4096;
    const char* Bsc = (const char*)pool + 8192 + cur * 16384;
    asm volatile("s_waitcnt vmcnt(0)" ::: "memory");
    __syncthreads();

    if (tt < 15) {
      const int k0 = (tt + 1) * 32;
      if (w < 4) GLL16(aSrc + k0, (char*)pool + (cur ^ 1) * 4096 + aDst);
#pragma unroll
      for (int i = 0; i < 2; ++i)
        GLL16(bSrc[i] + k0, (char*)pool + (cur ^ 1) * 16384 + bDst[i]);
    }

    bhalf8 af[2], bfv[4];
#pragma unroll
    for (int i = 0; i < 2; ++i) af[i] = *(const bhalf8*)(Asc + aOff[i]);
#pragma unroll
    for (int j = 0; j < 4; ++j) bfv[j] = *(const bhalf8*)(Bsc + bOff[j]);
#pragma unroll
    for (int i = 0; i < 2; ++i)
#pragma unroll
      for (int j = 0; j < 4; ++j)
        acc[i][j] = __builtin_amdgcn_mfma_f32_16x16x32_bf16(af[i], bfv[j], acc[i][j], 0, 0, 0);
  }

  __syncthreads();
#pragma unroll
  for (int i = 0; i < 2; ++i)
#pragma unroll
    for (int j = 0; j < 4; ++j)
#pragma unroll
      for (int q = 0; q < 4; ++q) {
        int row = wr * 32 + i * 16 + fg * 4 + q;
        int col = wc * 64 + j * 16 + fr;
        float vv = acc[i][j][q];
        vv = vv > 0.f ? vv : 0.f;
        pool[row * 264 + col] = f2bf(vv);
      }
  __syncthreads();

  if (w < 4) {
    f32x4 acc3 = (f32x4){0.f, 0.f, 0.f, 0.f};
    const int arow = w * 16 + fr;
#pragma unroll
    for (int ks = 0; ks < 8; ++ks) {
      bhalf8 a = *(const bhalf8*)&pool[arow * 264 + ks * 32 + fg * 8];
      bhalf8 b = *(const bhalf8*)&W2s[fr][ks * 32 + fg * 8];
      acc3 = __builtin_amdgcn_mfma_f32_16x16x32_bf16(a, b, acc3, 0, 0, 0);
    }
    if (fr < 10) {
#pragma unroll
      for (int q = 0; q < 4; ++q) {
        size_t row = rbase + w * 16 + fg * 4 + q;
        float vv = acc3[q];
        out[row * 10 + fr] = vv > 0.f ? vv : 0.f;
      }
    }
  }
}

extern "C" void kernel_launch(void* const* d_in, const int* in_sizes, int n_in,
                              void* d_out, int out_size, void* d_ws, size_t ws_size,
                              hipStream_t stream) {
  const float* x  = (const float*)d_in[0];
  const float* W0 = (const float*)d_in[1];
  const float* W1 = (const float*)d_in[2];
  const float* W2 = (const float*)d_in[3];
  float* out = (float*)d_out;

  char* ws = (char*)d_ws;
  u16* m1  = (u16*)(ws);                    // 32768x512 bf16 = 33554432 B
  u16* W0b = (u16*)(ws + 33554432);         // 512x832 = 851968 B
  u16* W1b = (u16*)(ws + 34406400);         // 256x512 = 262144 B
  u16* W2b = (u16*)(ws + 34668544);         // 16x256  = 8192 B

  // allow 128 KB dynamic LDS for gemm1_p8 (host-side attr, graph-capture safe)
  hipFuncSetAttribute((const void*)gemm1_p8,
                      hipFuncAttributeMaxDynamicSharedMemorySize, 131072);

  cvt_weights<<<dim3((W0E + W1E + W2E + 255) / 256), dim3(256), 0, stream>>>(
      W0, W1, W2, W0b, W1b, W2b);

  // m1 = relu(x @ W0^T): 256 row-tiles, full N=512, 8-phase schedule
  gemm1_p8<<<dim3(256), dim3(512), 131072, stream>>>(x, W0b, m1);

  // out = relu(relu(m1 @ W1^T) @ W2^T)
  gemm23<<<dim3(512), dim3(512), 0, stream>>>(m1, W1b, W2b, out);
}